// Round 4
// baseline (442.239 us; speedup 1.0000x reference)
//
#include <hip/hip_runtime.h>
#include <hip/hip_bf16.h>
#include <cstdint>
#include <cstddef>

// FP32 in/out. Compute: fp32 -> bf16 -> MFMA (fp32 acc) -> fp32 out.
typedef unsigned short u16;
typedef __attribute__((ext_vector_type(8))) __bf16 bf16x8;
typedef __attribute__((ext_vector_type(8))) unsigned short u16x8;
typedef __attribute__((ext_vector_type(4))) float f32x4;

__device__ __forceinline__ void gload_lds16(const void* g, void* l) {
    __builtin_amdgcn_global_load_lds(
        (const __attribute__((address_space(1))) unsigned int*)g,
        (__attribute__((address_space(3))) unsigned int*)l,
        16, 0, 0);
}

__device__ __forceinline__ u16 f2bf(float f) {  // RNE
    union { float f; unsigned int u; } v; v.f = f;
    unsigned int r = v.u + 0x7fffu + ((v.u >> 16) & 1u);
    return (u16)(r >> 16);
}

__device__ __forceinline__ float gelu_tanh(float x) {
    // 0.5x(1+tanh(0.79788456(x+0.044715x^3))); tanh via v_exp_f32.
    // Max |err| vs exact erf-GELU ~1e-3, << 7.8e-2 budget.
    const float z = 0.7978845608028654f * x * (1.0f + 0.044715f * x * x);
    const float t = __builtin_amdgcn_exp2f(2.885390081777927f * z);  // e^{2z}
    const float th = 1.0f - 2.0f * __builtin_amdgcn_rcpf(t + 1.0f);
    return 0.5f * x * (1.0f + th);
}

// C = act(A @ Bt^T + bias). A: MxK bf16 (k-contig). Bt: NxK bf16 (k-contig).
// A-fragments: direct global->VGPR (coalesced 64B/row segments, mostly L2/L3
// hits). B: LDS staging via global_load_lds with XOR source-granule swizzle
// (fragment ds_read_b128 is 2-way-aliased only = free). Epilogue: 4x 32-row
// LDS transpose chunks -> coalesced vector stores. FULLY UNROLLED epilogue:
// all acc[] indices compile-time => acc stays in VGPRs (no scratch; the R3
// rolled version scratch-demoted acc and broke graph replay).
// M%128==0, N%128==0, K%32==0.
template <int GELU, int OUT_BF16>
__global__ void gemm_adirect(const u16* __restrict__ A,
                             const u16* __restrict__ Bt,
                             const float* __restrict__ bias,
                             void* __restrict__ Cv,
                             int M, int N, int K) {
    // K-loop: Bs = 8 KB staging. Epilogue: 32 rows x 132 dwords = 16896 B.
    __shared__ __align__(16) char smem[16896];
    u16* Bs = (u16*)smem;
    float* Ct = (float*)smem;

    const int tid  = threadIdx.x;  // 256
    const int lane = tid & 63;
    const int wave = tid >> 6;
    const int wm   = (wave >> 1) * 64;
    const int wn   = (wave & 1) * 64;
    const int mrow = lane & 15;
    const int half = lane >> 4;

    const size_t ldb = (size_t)K * 2;  // row stride bytes
    const char* Bb = (const char*)(Bt + (size_t)blockIdx.y * 128 * K);
    const char* Ab = (const char*)A;

    // B staging: 512 granules of 16B; 2/thread; SOURCE granule swizzled so
    // LDS granule (row,slot) holds global granule slot^((row>>1)&3).
    const int r0 = tid >> 2, g0 = tid & 3;
    const int r1 = r0 + 64;
    const size_t boff0 = (size_t)r0 * ldb + (size_t)((g0 ^ ((r0 >> 1) & 3)) << 4);
    const size_t boff1 = (size_t)r1 * ldb + (size_t)((g0 ^ ((r1 >> 1) & 3)) << 4);

    // A-fragment global byte offsets (per mi); k advances by 64 B/iter
    size_t aoff[4];
#pragma unroll
    for (int mi = 0; mi < 4; ++mi)
        aoff[mi] = ((size_t)(blockIdx.x * 128 + wm + mi * 16 + mrow)) * ldb
                 + (size_t)(half << 4);

    // B-fragment LDS byte addresses (per ni), swizzle-corrected
    int blds[4];
#pragma unroll
    for (int t = 0; t < 4; ++t) {
        const int rb = wn + t * 16 + mrow;
        blds[t] = rb * 64 + ((half ^ ((rb >> 1) & 3)) << 4);
    }

    f32x4 acc[4][4];
#pragma unroll
    for (int i = 0; i < 4; ++i)
#pragma unroll
        for (int j = 0; j < 4; ++j) acc[i][j] = f32x4{0.f, 0.f, 0.f, 0.f};

    for (int k0 = 0; k0 < K; k0 += 32) {
        const size_t kb = (size_t)k0 * 2;
        gload_lds16(Bb + boff0 + kb, (char*)Bs + tid * 16);
        gload_lds16(Bb + boff1 + kb, (char*)Bs + (tid + 256) * 16);

        bf16x8 a[4];
#pragma unroll
        for (int mi = 0; mi < 4; ++mi)
            a[mi] = *(const bf16x8*)(Ab + aoff[mi] + kb);

        __syncthreads();  // vmcnt(0) drain: B tile (and a[]) resident

        bf16x8 bfr[4];
#pragma unroll
        for (int t = 0; t < 4; ++t)
            bfr[t] = *(const bf16x8*)((const char*)Bs + blds[t]);

#pragma unroll
        for (int mi = 0; mi < 4; ++mi)
#pragma unroll
            for (int ni = 0; ni < 4; ++ni)
                acc[mi][ni] = __builtin_amdgcn_mfma_f32_16x16x32_bf16(
                    a[mi], bfr[ni], acc[mi][ni], 0, 0, 0);

        __syncthreads();  // LDS reads done before next stage overwrites
    }

    // Epilogue. C/D layout (m89): block row = wm + mi*16 + half*4 + r,
    // block col = wn + mrow + ni*16. Chunk c covers block rows 32c..32c+31;
    // waves with wm==0 own chunks 0,1; wm==64 own 2,3. Ct stride 132 dwords
    // (bank-balanced, rows stay 16B-aligned).
    const int lrow0 = wm + half * 4;
    const int lcol0 = wn + mrow;
    const int growbase = blockIdx.x * 128;
    const int gcolbase = blockIdx.y * 128;
    const int rr_rd = tid >> 3, cs_rd = (tid & 7) * 16;

#pragma unroll
    for (int c = 0; c < 4; ++c) {
        __syncthreads();  // prior chunk reads (or K-loop reads) done
        if ((wm >> 6) == (c >> 1)) {
            const int mi0 = (c & 1) * 2;  // compile-time after unroll
#pragma unroll
            for (int dmi = 0; dmi < 2; ++dmi) {
                const int mi = mi0 + dmi;
#pragma unroll
                for (int ni = 0; ni < 4; ++ni) {
                    const int col = lcol0 + ni * 16;
                    const float bv = bias[gcolbase + col];
#pragma unroll
                    for (int r = 0; r < 4; ++r) {
                        const int rr = (mi * 16 + lrow0 + r) & 31;
                        float v = acc[mi][ni][r] + bv;
                        if (GELU) v = gelu_tanh(v);
                        Ct[rr * 132 + col] = v;
                    }
                }
            }
        }
        __syncthreads();  // chunk written
        const float* ct = &Ct[rr_rd * 132 + cs_rd];
        const f32x4 v0 = *(const f32x4*)(ct);
        const f32x4 v1 = *(const f32x4*)(ct + 4);
        const f32x4 v2 = *(const f32x4*)(ct + 8);
        const f32x4 v3 = *(const f32x4*)(ct + 12);
        const int grow = growbase + 32 * c + rr_rd;
        if (OUT_BF16) {
            u16x8 lo, hi;
#pragma unroll
            for (int j = 0; j < 4; ++j) {
                lo[j] = f2bf(v0[j]); lo[j + 4] = f2bf(v1[j]);
                hi[j] = f2bf(v2[j]); hi[j + 4] = f2bf(v3[j]);
            }
            u16* p = (u16*)Cv + (size_t)grow * N + gcolbase + cs_rd;
            *(u16x8*)(p)     = lo;
            *(u16x8*)(p + 8) = hi;
        } else {
            float* p = (float*)Cv + (size_t)grow * N + gcolbase + cs_rd;
            *(f32x4*)(p)      = v0;
            *(f32x4*)(p + 4)  = v1;
            *(f32x4*)(p + 8)  = v2;
            *(f32x4*)(p + 12) = v3;
        }
    }
}

// dst[c][r] = bf16(src[r][c]); src fp32 RxC, dst bf16 CxR. R,C %32==0.
__global__ void transpose_cvt_bf16(const float* __restrict__ src,
                                   u16* __restrict__ dst, int R, int C) {
    __shared__ u16 t[32][33];
    const int bx = blockIdx.x * 32;
    const int by = blockIdx.y * 32;
    const int x = threadIdx.x, y = threadIdx.y;  // 32 x 8
    for (int i = 0; i < 32; i += 8)
        t[y + i][x] = f2bf(src[(size_t)(by + y + i) * C + (bx + x)]);
    __syncthreads();
    for (int i = 0; i < 32; i += 8)
        dst[(size_t)(bx + y + i) * R + (by + x)] = t[x][y + i];
}

// flat fp32 -> bf16, n % 1024 == 0
__global__ void cvt_bf16(const float* __restrict__ src, u16* __restrict__ dst,
                         long long n) {
    const long long i = ((long long)blockIdx.x * blockDim.x + threadIdx.x) * 4;
    if (i + 3 < n) {
        const float4 v = *(const float4*)(src + i);
        ushort4 o;
        o.x = f2bf(v.x); o.y = f2bf(v.y); o.z = f2bf(v.z); o.w = f2bf(v.w);
        *(ushort4*)(dst + i) = o;
    }
}

// out[b, 0, :] = hs[b, 0, :]  (fp32)
__global__ void fixup_first_token(const float* __restrict__ hs,
                                  float* __restrict__ out, int S, int D) {
    const size_t base = (size_t)blockIdx.x * S * D;
    for (int i = threadIdx.x; i < D; i += blockDim.x)
        out[base + i] = hs[base + i];
}

extern "C" void kernel_launch(void* const* d_in, const int* in_sizes, int n_in,
                              void* d_out, int out_size, void* d_ws, size_t ws_size,
                              hipStream_t stream) {
    const float* X  = (const float*)d_in[0];  // [B,S,D] fp32
    const float* W1 = (const float*)d_in[1];  // [D,H]
    const float* b1 = (const float*)d_in[2];  // [H]
    const float* W2 = (const float*)d_in[3];  // [H,D]
    const float* b2 = (const float*)d_in[4];  // [D]
    float* out = (float*)d_out;

    const int B = 8, S = 2048, D = 1024, H = 2048;
    const int M = B * S;  // 16384

    // ws: W1T bf16 HxD (4MB) | W2T bf16 DxH (4MB) | Xb bf16 CMxD | Hb bf16 CMxH
    u16* W1T = (u16*)d_ws;
    u16* W2T = W1T + (size_t)H * D;
    u16* Xb  = W2T + (size_t)D * H;
    const size_t wfixed = (size_t)H * D * 2 * 2;
    const size_t perrow = (size_t)(D + H) * 2;
    size_t avail_rows = (ws_size > wfixed) ? (ws_size - wfixed) / perrow : 0;
    int CM = (int)((avail_rows / 128) * 128);
    if (CM > M) CM = M;
    if (CM < 128) CM = 128;
    u16* Hb = Xb + (size_t)CM * D;

    dim3 tb(32, 8);
    transpose_cvt_bf16<<<dim3(H / 32, D / 32), tb, 0, stream>>>(W1, W1T, D, H);
    transpose_cvt_bf16<<<dim3(D / 32, H / 32), tb, 0, stream>>>(W2, W2T, H, D);

    for (int m0 = 0; m0 < M; m0 += CM) {
        const int rows = (M - m0 < CM) ? (M - m0) : CM;
        const long long n = (long long)rows * D;
        cvt_bf16<<<dim3((unsigned)(n / 1024)), dim3(256), 0, stream>>>(
            X + (size_t)m0 * D, Xb, n);
        dim3 g1(rows / 128, H / 128);
        gemm_adirect<1, 1><<<g1, dim3(256), 0, stream>>>(
            Xb, W1T, b1, Hb, rows, H, D);
        dim3 g2(rows / 128, D / 128);
        gemm_adirect<0, 0><<<g2, dim3(256), 0, stream>>>(
            Hb, W2T, b2, out + (size_t)m0 * D, rows, D, H);
    }

    fixup_first_token<<<dim3(B), dim3(256), 0, stream>>>(X, out, S, D);
}

// Round 5
// 327.927 us; speedup vs baseline: 1.3486x; 1.3486x over previous
//
#include <hip/hip_runtime.h>
#include <hip/hip_bf16.h>
#include <cstdint>
#include <cstddef>

// FP32 in/out. Compute: fp32 -> bf16 -> MFMA (fp32 acc) -> fp32 out.
typedef unsigned short u16;
typedef __attribute__((ext_vector_type(8))) __bf16 bf16x8;
typedef __attribute__((ext_vector_type(8))) unsigned short u16x8;
typedef __attribute__((ext_vector_type(4))) float f32x4;

__device__ __forceinline__ void gload_lds16(const void* g, void* l) {
    __builtin_amdgcn_global_load_lds(
        (const __attribute__((address_space(1))) unsigned int*)g,
        (__attribute__((address_space(3))) unsigned int*)l,
        16, 0, 0);
}

__device__ __forceinline__ u16 f2bf(float f) {  // RNE
    union { float f; unsigned int u; } v; v.f = f;
    unsigned int r = v.u + 0x7fffu + ((v.u >> 16) & 1u);
    return (u16)(r >> 16);
}

__device__ __forceinline__ float gelu_tanh(float x) {
    // 0.5x(1+tanh(0.79788456(x+0.044715x^3))); tanh via v_exp_f32.
    // Max |err| vs exact erf-GELU ~1e-3, << 7.8e-2 budget.
    const float z = 0.7978845608028654f * x * (1.0f + 0.044715f * x * x);
    const float t = __builtin_amdgcn_exp2f(2.885390081777927f * z);  // e^{2z}
    const float th = 1.0f - 2.0f * __builtin_amdgcn_rcpf(t + 1.0f);
    return 0.5f * x * (1.0f + th);
}

// C = act(A @ Bt^T + bias). A: MxK bf16 (k-contig). Bt: NxK bf16 (k-contig).
// m97 K-loop: BOTH tiles staged via global_load_lds (coalesced DMA; R4's
// A-direct gather was latency-bound — reverted). XOR source-granule swizzle
// on both tiles: LDS slot (row,g) holds global granule g^((row>>1)&3), so
// fragment ds_read_b128 is conflict-free (R4-verified: SQ_LDS_BANK_CONFLICT
// 8.4e6 -> 0). Epilogue: 4x 32-row LDS-transpose chunks -> coalesced vector
// stores; FULLY UNROLLED so acc[] stays in VGPRs (R3: rolled version
// scratch-demoted acc and broke graph replay). M%128==0, N%128==0, K%32==0.
template <int GELU, int OUT_BF16>
__global__ void gemm_bt(const u16* __restrict__ A,
                        const u16* __restrict__ Bt,
                        const float* __restrict__ bias,
                        void* __restrict__ Cv,
                        int M, int N, int K) {
    // K-loop: As 8KB + Bs 8KB. Epilogue: 32 rows x 132 dwords = 16896 B.
    __shared__ __align__(16) char smem[16896];
    u16* As = (u16*)smem;           // [128 rows][4 granules of 16B]
    u16* Bs = (u16*)(smem + 8192);
    float* Ct = (float*)smem;

    const int tid  = threadIdx.x;  // 256
    const int lane = tid & 63;
    const int wave = tid >> 6;
    const int wm   = (wave >> 1) * 64;
    const int wn   = (wave & 1) * 64;
    const int mrow = lane & 15;
    const int half = lane >> 4;

    const size_t ldb = (size_t)K * 2;  // row stride bytes
    const char* Ab = (const char*)(A + (size_t)blockIdx.x * 128 * K);
    const char* Bb = (const char*)(Bt + (size_t)blockIdx.y * 128 * K);

    // Staging: 512 granules of 16B per tile; 2/thread; SOURCE offset swizzled
    // so LDS slot (r,g) holds global granule g^((r>>1)&3).
    const int r0 = tid >> 2, g0 = tid & 3;
    const int r1 = r0 + 64;
    const size_t soff0 = (size_t)r0 * ldb + (size_t)((g0 ^ ((r0 >> 1) & 3)) << 4);
    const size_t soff1 = (size_t)r1 * ldb + (size_t)((g0 ^ ((r1 >> 1) & 3)) << 4);

    // Fragment LDS byte addresses (swizzle-corrected), constant over K.
    int alds[4], blds[4];
#pragma unroll
    for (int t = 0; t < 4; ++t) {
        const int ra = wm + t * 16 + mrow;
        alds[t] = ra * 64 + ((half ^ ((ra >> 1) & 3)) << 4);
        const int rb = wn + t * 16 + mrow;
        blds[t] = rb * 64 + ((half ^ ((rb >> 1) & 3)) << 4);
    }

    f32x4 acc[4][4];
#pragma unroll
    for (int i = 0; i < 4; ++i)
#pragma unroll
        for (int j = 0; j < 4; ++j) acc[i][j] = f32x4{0.f, 0.f, 0.f, 0.f};

    for (int k0 = 0; k0 < K; k0 += 32) {
        const size_t kb = (size_t)k0 * 2;
        gload_lds16(Ab + soff0 + kb, (char*)As + tid * 16);
        gload_lds16(Ab + soff1 + kb, (char*)As + (tid + 256) * 16);
        gload_lds16(Bb + soff0 + kb, (char*)Bs + tid * 16);
        gload_lds16(Bb + soff1 + kb, (char*)Bs + (tid + 256) * 16);
        __syncthreads();  // vmcnt(0) drain at barrier: tiles resident

        bf16x8 af[4], bfr[4];
#pragma unroll
        for (int t = 0; t < 4; ++t) {
            af[t]  = *(const bf16x8*)((const char*)As + alds[t]);
            bfr[t] = *(const bf16x8*)((const char*)Bs + blds[t]);
        }

#pragma unroll
        for (int mi = 0; mi < 4; ++mi)
#pragma unroll
            for (int ni = 0; ni < 4; ++ni)
                acc[mi][ni] = __builtin_amdgcn_mfma_f32_16x16x32_bf16(
                    af[mi], bfr[ni], acc[mi][ni], 0, 0, 0);

        __syncthreads();  // LDS reads done before next stage overwrites
    }

    // Epilogue. C/D layout (m89): block row = wm + mi*16 + half*4 + r,
    // block col = wn + mrow + ni*16. Chunk c covers block rows 32c..32c+31;
    // wm=0 waves own chunks 0,1; wm=64 own 2,3. Ct stride 132 dwords
    // (bank-balanced, rows 16B-aligned).
    const int lrow0 = wm + half * 4;
    const int lcol0 = wn + mrow;
    const int growbase = blockIdx.x * 128;
    const int gcolbase = blockIdx.y * 128;
    const int rr_rd = tid >> 3, cs_rd = (tid & 7) * 16;

#pragma unroll
    for (int c = 0; c < 4; ++c) {
        __syncthreads();  // prior chunk reads (or K-loop reads) done
        if ((wm >> 6) == (c >> 1)) {
            const int mi0 = (c & 1) * 2;  // compile-time after unroll
#pragma unroll
            for (int dmi = 0; dmi < 2; ++dmi) {
                const int mi = mi0 + dmi;
#pragma unroll
                for (int ni = 0; ni < 4; ++ni) {
                    const int col = lcol0 + ni * 16;
                    const float bv = bias[gcolbase + col];
#pragma unroll
                    for (int r = 0; r < 4; ++r) {
                        const int rr = (mi * 16 + lrow0 + r) & 31;
                        float v = acc[mi][ni][r] + bv;
                        if (GELU) v = gelu_tanh(v);
                        Ct[rr * 132 + col] = v;
                    }
                }
            }
        }
        __syncthreads();  // chunk written
        const float* ct = &Ct[rr_rd * 132 + cs_rd];
        const f32x4 v0 = *(const f32x4*)(ct);
        const f32x4 v1 = *(const f32x4*)(ct + 4);
        const f32x4 v2 = *(const f32x4*)(ct + 8);
        const f32x4 v3 = *(const f32x4*)(ct + 12);
        const int grow = growbase + 32 * c + rr_rd;
        if (OUT_BF16) {
            u16x8 lo, hi;
#pragma unroll
            for (int j = 0; j < 4; ++j) {
                lo[j] = f2bf(v0[j]); lo[j + 4] = f2bf(v1[j]);
                hi[j] = f2bf(v2[j]); hi[j + 4] = f2bf(v3[j]);
            }
            u16* p = (u16*)Cv + (size_t)grow * N + gcolbase + cs_rd;
            *(u16x8*)(p)     = lo;
            *(u16x8*)(p + 8) = hi;
        } else {
            float* p = (float*)Cv + (size_t)grow * N + gcolbase + cs_rd;
            *(f32x4*)(p)      = v0;
            *(f32x4*)(p + 4)  = v1;
            *(f32x4*)(p + 8)  = v2;
            *(f32x4*)(p + 12) = v3;
        }
    }
}

// dst[c][r] = bf16(src[r][c]); src fp32 RxC, dst bf16 CxR. R,C %32==0.
__global__ void transpose_cvt_bf16(const float* __restrict__ src,
                                   u16* __restrict__ dst, int R, int C) {
    __shared__ u16 t[32][33];
    const int bx = blockIdx.x * 32;
    const int by = blockIdx.y * 32;
    const int x = threadIdx.x, y = threadIdx.y;  // 32 x 8
    for (int i = 0; i < 32; i += 8)
        t[y + i][x] = f2bf(src[(size_t)(by + y + i) * C + (bx + x)]);
    __syncthreads();
    for (int i = 0; i < 32; i += 8)
        dst[(size_t)(bx + y + i) * R + (by + x)] = t[x][y + i];
}

// flat fp32 -> bf16, n % 1024 == 0
__global__ void cvt_bf16(const float* __restrict__ src, u16* __restrict__ dst,
                         long long n) {
    const long long i = ((long long)blockIdx.x * blockDim.x + threadIdx.x) * 4;
    if (i + 3 < n) {
        const float4 v = *(const float4*)(src + i);
        ushort4 o;
        o.x = f2bf(v.x); o.y = f2bf(v.y); o.z = f2bf(v.z); o.w = f2bf(v.w);
        *(ushort4*)(dst + i) = o;
    }
}

// out[b, 0, :] = hs[b, 0, :]  (fp32)
__global__ void fixup_first_token(const float* __restrict__ hs,
                                  float* __restrict__ out, int S, int D) {
    const size_t base = (size_t)blockIdx.x * S * D;
    for (int i = threadIdx.x; i < D; i += blockDim.x)
        out[base + i] = hs[base + i];
}

extern "C" void kernel_launch(void* const* d_in, const int* in_sizes, int n_in,
                              void* d_out, int out_size, void* d_ws, size_t ws_size,
                              hipStream_t stream) {
    const float* X  = (const float*)d_in[0];  // [B,S,D] fp32
    const float* W1 = (const float*)d_in[1];  // [D,H]
    const float* b1 = (const float*)d_in[2];  // [H]
    const float* W2 = (const float*)d_in[3];  // [H,D]
    const float* b2 = (const float*)d_in[4];  // [D]
    float* out = (float*)d_out;

    const int B = 8, S = 2048, D = 1024, H = 2048;
    const int M = B * S;  // 16384

    // ws: W1T bf16 HxD (4MB) | W2T bf16 DxH (4MB) | Xb bf16 CMxD | Hb bf16 CMxH
    u16* W1T = (u16*)d_ws;
    u16* W2T = W1T + (size_t)H * D;
    u16* Xb  = W2T + (size_t)D * H;
    const size_t wfixed = (size_t)H * D * 2 * 2;
    const size_t perrow = (size_t)(D + H) * 2;
    size_t avail_rows = (ws_size > wfixed) ? (ws_size - wfixed) / perrow : 0;
    int CM = (int)((avail_rows / 128) * 128);
    if (CM > M) CM = M;
    if (CM < 128) CM = 128;
    u16* Hb = Xb + (size_t)CM * D;

    dim3 tb(32, 8);
    transpose_cvt_bf16<<<dim3(H / 32, D / 32), tb, 0, stream>>>(W1, W1T, D, H);
    transpose_cvt_bf16<<<dim3(D / 32, H / 32), tb, 0, stream>>>(W2, W2T, H, D);

    for (int m0 = 0; m0 < M; m0 += CM) {
        const int rows = (M - m0 < CM) ? (M - m0) : CM;
        const long long n = (long long)rows * D;
        cvt_bf16<<<dim3((unsigned)(n / 1024)), dim3(256), 0, stream>>>(
            X + (size_t)m0 * D, Xb, n);
        dim3 g1(rows / 128, H / 128);
        gemm_bt<1, 1><<<g1, dim3(256), 0, stream>>>(
            Xb, W1T, b1, Hb, rows, H, D);
        dim3 g2(rows / 128, D / 128);
        gemm_bt<0, 0><<<g2, dim3(256), 0, stream>>>(
            Hb, W2T, b2, out + (size_t)m0 * D, rows, D, H);
    }

    fixup_first_token<<<dim3(B), dim3(256), 0, stream>>>(X, out, S, D);
}

// Round 6
// 297.399 us; speedup vs baseline: 1.4870x; 1.1027x over previous
//
#include <hip/hip_runtime.h>
#include <hip/hip_bf16.h>
#include <cstdint>
#include <cstddef>

// FP32 in/out. Compute: fp32 -> bf16 -> MFMA (fp32 acc) -> fp32 out.
typedef unsigned short u16;
typedef __attribute__((ext_vector_type(8))) __bf16 bf16x8;
typedef __attribute__((ext_vector_type(8))) unsigned short u16x8;
typedef __attribute__((ext_vector_type(4))) float f32x4;

__device__ __forceinline__ void gload_lds16(const void* g, void* l) {
    __builtin_amdgcn_global_load_lds(
        (const __attribute__((address_space(1))) unsigned int*)g,
        (__attribute__((address_space(3))) unsigned int*)l,
        16, 0, 0);
}

__device__ __forceinline__ u16 f2bf(float f) {  // RNE
    union { float f; unsigned int u; } v; v.f = f;
    unsigned int r = v.u + 0x7fffu + ((v.u >> 16) & 1u);
    return (u16)(r >> 16);
}

__device__ __forceinline__ float gelu_tanh(float x) {
    // 0.5x(1+tanh(0.79788456(x+0.044715x^3))); max |err| vs erf-GELU ~1e-3.
    const float z = 0.7978845608028654f * x * (1.0f + 0.044715f * x * x);
    const float t = __builtin_amdgcn_exp2f(2.885390081777927f * z);  // e^{2z}
    const float th = 1.0f - 2.0f * __builtin_amdgcn_rcpf(t + 1.0f);
    return 0.5f * x * (1.0f + th);
}

// C = act(A @ Bt^T + bias). A: MxK bf16 (k-contig). Bt: NxK bf16 (k-contig).
// BK=64 K-loop (2x 32-K MFMA substeps per barrier pair — halves drain count
// vs R5's BK=32 at same LDS bank behavior). Both tiles staged via
// global_load_lds with XOR source-granule swizzle: LDS slot (r,s) holds
// global granule s^(r&7); fragment ds_read_b128 is 2-way-aliased = free
// (R5-verified: SQ_LDS_BANK_CONFLICT == 0). Epilogue: 4x 32-row LDS
// transpose chunks -> coalesced vector stores; fully unrolled so acc[]
// stays in VGPRs (R3: rolled version scratch-demoted acc, broke replay).
// SKIP_S: suppress stores of rows with (row0+row) % 2048 == 0 (first-token
// rows, pre-written by prep). M%128==0, N%128==0, K%64==0.
template <int GELU, int OUT_BF16, int SKIP_S>
__global__ void gemm_bt(const u16* __restrict__ A,
                        const u16* __restrict__ Bt,
                        const float* __restrict__ bias,
                        void* __restrict__ Cv,
                        int M, int N, int K, int row0) {
    // K-loop: As 16KB + Bs 16KB. Epilogue reuses first 16896 B as fp32 Ct.
    __shared__ __align__(16) char smem[32768];
    u16* As = (u16*)smem;
    u16* Bs = (u16*)(smem + 16384);
    float* Ct = (float*)smem;

    const int tid  = threadIdx.x;  // 256
    const int lane = tid & 63;
    const int wave = tid >> 6;
    const int wm   = (wave >> 1) * 64;
    const int wn   = (wave & 1) * 64;
    const int mrow = lane & 15;
    const int half = lane >> 4;

    const size_t ldb = (size_t)K * 2;  // row stride bytes
    const char* Ab = (const char*)(A + (size_t)blockIdx.x * 128 * K);
    const char* Bb = (const char*)(Bt + (size_t)blockIdx.y * 128 * K);

    // Staging: per tile 128 rows x 128 B = 1024 granules of 16 B; 4/thread.
    // LDS linear granule L -> row r=L>>3, slot s=L&7, content = global
    // granule s^(r&7) of row r.
    size_t goff[4];
    int loff[4];
#pragma unroll
    for (int i = 0; i < 4; ++i) {
        const int L = tid + 256 * i, r = L >> 3, s = L & 7;
        goff[i] = (size_t)r * ldb + (size_t)((s ^ (r & 7)) << 4);
        loff[i] = L << 4;
    }

    // Fragment LDS byte addresses per 32-K substep j, swizzle-corrected.
    int alds[2][4], blds[2][4];
#pragma unroll
    for (int j = 0; j < 2; ++j)
#pragma unroll
        for (int t = 0; t < 4; ++t) {
            const int g = j * 4 + half;
            const int ra = wm + t * 16 + mrow;
            alds[j][t] = ra * 128 + ((g ^ (ra & 7)) << 4);
            const int rb = wn + t * 16 + mrow;
            blds[j][t] = rb * 128 + ((g ^ (rb & 7)) << 4);
        }

    f32x4 acc[4][4];
#pragma unroll
    for (int i = 0; i < 4; ++i)
#pragma unroll
        for (int j = 0; j < 4; ++j) acc[i][j] = f32x4{0.f, 0.f, 0.f, 0.f};

    for (int k0 = 0; k0 < K; k0 += 64) {
        const size_t kb = (size_t)k0 * 2;
#pragma unroll
        for (int i = 0; i < 4; ++i)
            gload_lds16(Ab + goff[i] + kb, (char*)As + loff[i]);
#pragma unroll
        for (int i = 0; i < 4; ++i)
            gload_lds16(Bb + goff[i] + kb, (char*)Bs + loff[i]);
        __syncthreads();  // vmcnt(0) drain: both tiles resident

#pragma unroll
        for (int j = 0; j < 2; ++j) {
            bf16x8 af[4], bfr[4];
#pragma unroll
            for (int t = 0; t < 4; ++t) {
                af[t]  = *(const bf16x8*)((const char*)As + alds[j][t]);
                bfr[t] = *(const bf16x8*)((const char*)Bs + blds[j][t]);
            }
#pragma unroll
            for (int mi = 0; mi < 4; ++mi)
#pragma unroll
                for (int ni = 0; ni < 4; ++ni)
                    acc[mi][ni] = __builtin_amdgcn_mfma_f32_16x16x32_bf16(
                        af[mi], bfr[ni], acc[mi][ni], 0, 0, 0);
        }
        __syncthreads();  // LDS reads done before next stage overwrites
    }

    // Epilogue. C/D layout (m89): block row = wm + mi*16 + half*4 + r,
    // block col = wn + mrow + ni*16. Chunk c covers rows 32c..32c+31; wm=0
    // waves own chunks 0,1; wm=64 own 2,3. Ct stride 132 dwords.
    const int lrow0 = wm + half * 4;
    const int lcol0 = wn + mrow;
    const int growbase = blockIdx.x * 128;
    const int gcolbase = blockIdx.y * 128;
    const int rr_rd = tid >> 3, cs_rd = (tid & 7) * 16;

#pragma unroll
    for (int c = 0; c < 4; ++c) {
        __syncthreads();  // prior chunk reads (or K-loop reads) done
        if ((wm >> 6) == (c >> 1)) {
            const int mi0 = (c & 1) * 2;  // compile-time after unroll
#pragma unroll
            for (int dmi = 0; dmi < 2; ++dmi) {
                const int mi = mi0 + dmi;
#pragma unroll
                for (int ni = 0; ni < 4; ++ni) {
                    const int col = lcol0 + ni * 16;
                    const float bv = bias[gcolbase + col];
#pragma unroll
                    for (int r = 0; r < 4; ++r) {
                        const int rr = (mi * 16 + lrow0 + r) & 31;
                        float v = acc[mi][ni][r] + bv;
                        if (GELU) v = gelu_tanh(v);
                        Ct[rr * 132 + col] = v;
                    }
                }
            }
        }
        __syncthreads();  // chunk written
        const int grow = growbase + 32 * c + rr_rd;
        const bool skip = SKIP_S && (((row0 + grow) & 2047) == 0);
        if (!skip) {
            const float* ct = &Ct[rr_rd * 132 + cs_rd];
            const f32x4 v0 = *(const f32x4*)(ct);
            const f32x4 v1 = *(const f32x4*)(ct + 4);
            const f32x4 v2 = *(const f32x4*)(ct + 8);
            const f32x4 v3 = *(const f32x4*)(ct + 12);
            if (OUT_BF16) {
                u16x8 lo, hi;
#pragma unroll
                for (int j = 0; j < 4; ++j) {
                    lo[j] = f2bf(v0[j]); lo[j + 4] = f2bf(v1[j]);
                    hi[j] = f2bf(v2[j]); hi[j + 4] = f2bf(v3[j]);
                }
                u16* p = (u16*)Cv + (size_t)grow * N + gcolbase + cs_rd;
                *(u16x8*)(p)     = lo;
                *(u16x8*)(p + 8) = hi;
            } else {
                float* p = (float*)Cv + (size_t)grow * N + gcolbase + cs_rd;
                *(f32x4*)(p)      = v0;
                *(f32x4*)(p + 4)  = v1;
                *(f32x4*)(p + 8)  = v2;
                *(f32x4*)(p + 12) = v3;
            }
        }
    }
}

__device__ __forceinline__ void tcvt_block(const float* __restrict__ src,
                                           u16* __restrict__ dst, int R, int C,
                                           int bx, int by, int x, int y,
                                           u16 (*t)[33]) {
    for (int i = 0; i < 32; i += 8)
        t[y + i][x] = f2bf(src[(size_t)(by + y + i) * C + (bx + x)]);
    __syncthreads();
    for (int i = 0; i < 32; i += 8)
        dst[(size_t)(bx + y + i) * R + (by + x)] = t[x][y + i];
}

// One fused prep dispatch (block-uniform branch on blockIdx ranges):
//   [0,2048)    transpose+cvt W1 (1024x2048 fp32 -> 2048x1024 bf16)
//   [2048,4096) transpose+cvt W2 (2048x1024 fp32 -> 1024x2048 bf16)
//   [4096,4104) out[b,0,:] = X[b,0,:]   (fp32 first-token rows; GEMM2 masks
//               these rows, so prep-before-GEMM2 ordering is irrelevant)
//   [4104,8200) grid-stride cvt X fp32 -> bf16 (16.78M elems, 4 passes)
__global__ void prep(const float* __restrict__ X, const float* __restrict__ W1,
                     const float* __restrict__ W2, u16* __restrict__ Xb,
                     u16* __restrict__ W1T, u16* __restrict__ W2T,
                     float* __restrict__ out, long long nX) {
    __shared__ u16 t[32][33];
    const int b = blockIdx.x, tid = threadIdx.x;
    const int x = tid & 31, y = tid >> 5;
    if (b < 2048) {            // W1: R=1024 rows, C=2048 cols; 64x32 blocks
        tcvt_block(W1, W1T, 1024, 2048, (b & 63) * 32, (b >> 6) * 32, x, y, t);
    } else if (b < 4096) {     // W2: R=2048, C=1024; 32x64 blocks
        const int bi = b - 2048;
        tcvt_block(W2, W2T, 2048, 1024, (bi & 31) * 32, (bi >> 5) * 32, x, y, t);
    } else if (b < 4104) {     // first-token copy, D=1024 floats = 256*float4
        const size_t base = (size_t)(b - 4096) * 2048 * 1024;
        *(float4*)(out + base + tid * 4) = *(const float4*)(X + base + tid * 4);
    } else {                   // cvt X
        const long long stride = (long long)4096 * 256 * 4;
        for (long long i = ((long long)(b - 4104) * 256 + tid) * 4; i < nX;
             i += stride) {
            const float4 v = *(const float4*)(X + i);
            ushort4 o;
            o.x = f2bf(v.x); o.y = f2bf(v.y); o.z = f2bf(v.z); o.w = f2bf(v.w);
            *(ushort4*)(Xb + i) = o;
        }
    }
}

extern "C" void kernel_launch(void* const* d_in, const int* in_sizes, int n_in,
                              void* d_out, int out_size, void* d_ws, size_t ws_size,
                              hipStream_t stream) {
    const float* X  = (const float*)d_in[0];  // [B,S,D] fp32
    const float* W1 = (const float*)d_in[1];  // [D,H]
    const float* b1 = (const float*)d_in[2];  // [H]
    const float* W2 = (const float*)d_in[3];  // [H,D]
    const float* b2 = (const float*)d_in[4];  // [D]
    float* out = (float*)d_out;

    const int B = 8, S = 2048, D = 1024, H = 2048;
    const int M = B * S;  // 16384

    // ws: W1T bf16 HxD (4MB) | W2T bf16 DxH (4MB) | Xb bf16 MxD (32MB) |
    //     Hb bf16 CMxH
    u16* W1T = (u16*)d_ws;
    u16* W2T = W1T + (size_t)H * D;
    u16* Xb  = W2T + (size_t)D * H;
    u16* Hb  = Xb + (size_t)M * D;
    const size_t wfixed = (size_t)H * D * 2 * 2 + (size_t)M * D * 2;  // 40 MB
    size_t avail_rows = (ws_size > wfixed) ? (ws_size - wfixed) / ((size_t)H * 2) : 0;
    int CM = (int)((avail_rows / 128) * 128);
    if (CM > M) CM = M;
    if (CM < 128) CM = 128;

    prep<<<dim3(8200), dim3(256), 0, stream>>>(
        X, W1, W2, Xb, W1T, W2T, out, (long long)M * D);

    for (int m0 = 0; m0 < M; m0 += CM) {
        const int rows = (M - m0 < CM) ? (M - m0) : CM;
        dim3 g1(rows / 128, H / 128);
        gemm_bt<1, 1, 0><<<g1, dim3(256), 0, stream>>>(
            Xb + (size_t)m0 * D, W1T, b1, Hb, rows, H, D, m0);
        dim3 g2(rows / 128, D / 128);
        gemm_bt<0, 0, 1><<<g2, dim3(256), 0, stream>>>(
            Hb, W2T, b2, out + (size_t)m0 * D, rows, D, H, m0);
    }
}